// Round 1
// baseline (111.983 us; speedup 1.0000x reference)
//
#include <hip/hip_runtime.h>

constexpr int N = 512;   // number of samples
constexpr int D = 256;   // feature dim
#define MARGIN 1.0f

// Block i: compute dist row i in LDS, then accumulate sum/count of
// relu(dist[i][j] - dist[i][k] + margin) over valid (j,k).
__global__ __launch_bounds__(256) void triplet_fused(
    const float* __restrict__ x, const int* __restrict__ tgt,
    float* __restrict__ acc) {
  __shared__ __align__(16) float xi[D];
  __shared__ __align__(16) float row[N];
  __shared__ __align__(16) float m[N];
  __shared__ float wsum[4], wcnt[4];

  const int i = blockIdx.x;
  const int tid = threadIdx.x;          // 256 threads
  const int ti = tgt[i];

  xi[tid] = x[(size_t)i * D + tid];
  __syncthreads();

  // squared norm of x_i (redundant per-thread, LDS broadcast reads)
  float sqi = 0.f;
  const float4* xiv = (const float4*)xi;
  #pragma unroll 8
  for (int d4 = 0; d4 < D / 4; ++d4) {
    float4 a = xiv[d4];
    sqi += a.x * a.x + a.y * a.y + a.z * a.z + a.w * a.w;
  }

  // distance row: row[j] = sqrt(max(sqi + sqj - 2*dot, 1e-16))
  for (int jj = 0; jj < 2; ++jj) {
    int j = tid + jj * 256;
    const float4* xj = (const float4*)(x + (size_t)j * D);
    float dot = 0.f, sqj = 0.f;
    #pragma unroll 4
    for (int d4 = 0; d4 < D / 4; ++d4) {
      float4 a = xiv[d4];
      float4 b = xj[d4];
      dot += a.x * b.x + a.y * b.y + a.z * b.z + a.w * b.w;
      sqj += b.x * b.x + b.y * b.y + b.z * b.z + b.w * b.w;
    }
    float dsq = sqi + sqj - 2.f * dot;
    row[j] = sqrtf(fmaxf(dsq, 1e-16f));
  }
  __syncthreads();

  // m[k] = dist[i][k] if t[k] != t[i] else +INF (so relu/count give 0)
  for (int kk = 0; kk < 2; ++kk) {
    int k = tid + kk * 256;
    m[k] = (tgt[k] != ti) ? row[k] : __builtin_inff();
  }
  __syncthreads();

  float sum = 0.f, cnt = 0.f;
  const float4* m4 = (const float4*)m;
  for (int jj = 0; jj < 2; ++jj) {
    int j = tid + jj * 256;
    bool valid = (tgt[j] == ti) && (j != i);
    // invalid j -> c = -INF -> t = -INF -> contributes 0 to sum and count
    float c = valid ? (row[j] + MARGIN) : -__builtin_inff();
    #pragma unroll 4
    for (int k4 = 0; k4 < N / 4; ++k4) {
      float4 mk = m4[k4];
      float t0 = c - mk.x;
      float t1 = c - mk.y;
      float t2 = c - mk.z;
      float t3 = c - mk.w;
      sum += fmaxf(t0, 0.f) + fmaxf(t1, 0.f) + fmaxf(t2, 0.f) + fmaxf(t3, 0.f);
      cnt += (t0 > 1e-16f ? 1.f : 0.f) + (t1 > 1e-16f ? 1.f : 0.f) +
             (t2 > 1e-16f ? 1.f : 0.f) + (t3 > 1e-16f ? 1.f : 0.f);
    }
  }

  // wave reduction (64-wide) then cross-wave via LDS
  #pragma unroll
  for (int off = 32; off > 0; off >>= 1) {
    sum += __shfl_down(sum, off);
    cnt += __shfl_down(cnt, off);
  }
  int wave = tid >> 6, lane = tid & 63;
  if (lane == 0) { wsum[wave] = sum; wcnt[wave] = cnt; }
  __syncthreads();
  if (tid == 0) {
    atomicAdd(&acc[0], wsum[0] + wsum[1] + wsum[2] + wsum[3]);
    atomicAdd(&acc[1], wcnt[0] + wcnt[1] + wcnt[2] + wcnt[3]);
  }
}

__global__ void triplet_finalize(const float* __restrict__ acc,
                                 float* __restrict__ out) {
  out[0] = acc[0] / (acc[1] + 1e-16f);
}

extern "C" void kernel_launch(void* const* d_in, const int* in_sizes, int n_in,
                              void* d_out, int out_size, void* d_ws, size_t ws_size,
                              hipStream_t stream) {
  const float* x = (const float*)d_in[0];   // [512, 256] fp32
  const int* tgt = (const int*)d_in[1];     // [512] int32
  float* out = (float*)d_out;               // scalar fp32
  float* acc = (float*)d_ws;                // acc[0]=sum, acc[1]=count

  hipMemsetAsync(acc, 0, 2 * sizeof(float), stream);
  triplet_fused<<<N, 256, 0, stream>>>(x, tgt, acc);
  triplet_finalize<<<1, 1, 0, stream>>>(acc, out);
}

// Round 2
// 97.565 us; speedup vs baseline: 1.1478x; 1.1478x over previous
//
#include <hip/hip_runtime.h>

constexpr int N = 512;   // number of samples
constexpr int D = 256;   // feature dim
#define MARGIN 1.0f

// Block i: compute dist row i, compact valid j list (t[j]==t[i], j!=i),
// then sum relu(dist[i][j] - dist[i][k] + margin) over valid (j,k).
// Valid j per i is ~8 (64 classes over 512 samples), so the triplet phase
// is ~400x less work than the full 512x512 sweep.
__global__ __launch_bounds__(256) void triplet_fused(
    const float* __restrict__ x, const int* __restrict__ tgt,
    float* __restrict__ acc) {
  __shared__ __align__(16) float xi[D];     // row i staged for broadcast
  __shared__ __align__(16) float m[N];      // dist row, +INF at positives
  __shared__ float clist[N];                // compacted c = d_ap + margin
  __shared__ int nv;
  __shared__ float wred[8];                 // 4 waves x {sum, cnt}

  const int i = blockIdx.x;
  const int tid = threadIdx.x;              // 256 threads
  const int ti = tgt[i];

  // stage xi; keep own element in a register for the sq reduction
  float xv = x[(size_t)i * D + tid];
  xi[tid] = xv;
  if (tid == 0) nv = 0;

  // sqi = ||x_i||^2 via block reduction (1 mul + shuffle tree)
  float p = xv * xv;
  #pragma unroll
  for (int off = 32; off > 0; off >>= 1) p += __shfl_down(p, off);
  int wave = tid >> 6, lane = tid & 63;
  if (lane == 0) wred[wave] = p;
  __syncthreads();
  const float sqi = wred[0] + wred[1] + wred[2] + wred[3];

  // distance row: thread t owns j = t and j = t+256.
  // One xi broadcast read per d4 serves both rows (halves LDS traffic).
  const int j0 = tid, j1 = tid + 256;
  const float4* xiv = (const float4*)xi;
  const float4* xj0 = (const float4*)(x + (size_t)j0 * D);
  const float4* xj1 = (const float4*)(x + (size_t)j1 * D);
  float dot0 = 0.f, dot1 = 0.f, sq0 = 0.f, sq1 = 0.f;
  #pragma unroll 4
  for (int d4 = 0; d4 < D / 4; ++d4) {
    float4 a  = xiv[d4];
    float4 b0 = xj0[d4];
    float4 b1 = xj1[d4];
    dot0 += a.x * b0.x + a.y * b0.y + a.z * b0.z + a.w * b0.w;
    sq0  += b0.x * b0.x + b0.y * b0.y + b0.z * b0.z + b0.w * b0.w;
    dot1 += a.x * b1.x + a.y * b1.y + a.z * b1.z + a.w * b1.w;
    sq1  += b1.x * b1.x + b1.y * b1.y + b1.z * b1.z + b1.w * b1.w;
  }
  float r0 = sqrtf(fmaxf(sqi + sq0 - 2.f * dot0, 1e-16f));
  float r1 = sqrtf(fmaxf(sqi + sq1 - 2.f * dot1, 1e-16f));

  const int t0 = tgt[j0], t1 = tgt[j1];
  m[j0] = (t0 != ti) ? r0 : __builtin_inff();   // +INF masks positives as k
  m[j1] = (t1 != ti) ? r1 : __builtin_inff();
  if (t0 == ti && j0 != i) { int s = atomicAdd(&nv, 1); clist[s] = r0 + MARGIN; }
  if (t1 == ti && j1 != i) { int s = atomicAdd(&nv, 1); clist[s] = r1 + MARGIN; }
  __syncthreads();

  // triplet phase: each thread owns k-pair m[2*tid], m[2*tid+1] (loop-invariant)
  float sum = 0.f, cnt = 0.f;
  const float2 mk = ((const float2*)m)[tid];    // 2-way bank alias: free
  const int n = nv;
  for (int v = 0; v < n; ++v) {
    float c = clist[v];                         // LDS broadcast
    float a0 = c - mk.x;
    float a1 = c - mk.y;
    sum += fmaxf(a0, 0.f) + fmaxf(a1, 0.f);
    cnt += (a0 > 1e-16f ? 1.f : 0.f) + (a1 > 1e-16f ? 1.f : 0.f);
  }

  // block reduction, one atomic pair per block
  #pragma unroll
  for (int off = 32; off > 0; off >>= 1) {
    sum += __shfl_down(sum, off);
    cnt += __shfl_down(cnt, off);
  }
  __syncthreads();                              // wred reuse
  if (lane == 0) { wred[wave] = sum; wred[4 + wave] = cnt; }
  __syncthreads();
  if (tid == 0) {
    atomicAdd(&acc[0], wred[0] + wred[1] + wred[2] + wred[3]);
    atomicAdd(&acc[1], wred[4] + wred[5] + wred[6] + wred[7]);
  }
}

__global__ void triplet_finalize(const float* __restrict__ acc,
                                 float* __restrict__ out) {
  out[0] = acc[0] / (acc[1] + 1e-16f);
}

extern "C" void kernel_launch(void* const* d_in, const int* in_sizes, int n_in,
                              void* d_out, int out_size, void* d_ws, size_t ws_size,
                              hipStream_t stream) {
  const float* x = (const float*)d_in[0];   // [512, 256] fp32
  const int* tgt = (const int*)d_in[1];     // [512] int32
  float* out = (float*)d_out;               // scalar fp32
  float* acc = (float*)d_ws;                // acc[0]=sum, acc[1]=count

  hipMemsetAsync(acc, 0, 2 * sizeof(float), stream);
  triplet_fused<<<N, 256, 0, stream>>>(x, tgt, acc);
  triplet_finalize<<<1, 1, 0, stream>>>(acc, out);
}

// Round 3
// 89.244 us; speedup vs baseline: 1.2548x; 1.0932x over previous
//
#include <hip/hip_runtime.h>

constexpr int N = 512;   // number of samples
constexpr int D = 256;   // feature dim
#define MARGIN 1.0f

// Block i: compute dist row i with COALESCED cooperative row reads
// (wave = 4 rows x 16-lane chunks), compact valid j list (t[j]==t[i], j!=i),
// then sum relu(dist[i][j] - dist[i][k] + margin) over valid (j,k).
__global__ __launch_bounds__(256) void triplet_fused(
    const float* __restrict__ x, const int* __restrict__ tgt,
    float* __restrict__ acc) {
  __shared__ __align__(16) float xi[D];     // row i staged for broadcast
  __shared__ __align__(16) float m[N];      // dist row, +INF at positives
  __shared__ float clist[N];                // compacted c = d_ap + margin
  __shared__ int nv;
  __shared__ float wred[8];                 // 4 waves x {sum, cnt}

  const int i = blockIdx.x;
  const int tid = threadIdx.x;              // 256 threads = 4 waves
  const int ti = tgt[i];
  const int wave = tid >> 6, lane = tid & 63;
  const int sub = lane & 15, rg = lane >> 4; // chunk-in-row, row-in-group

  // stage xi; keep own element in a register for the sq reduction
  float xv = x[(size_t)i * D + tid];
  xi[tid] = xv;
  if (tid == 0) nv = 0;

  // sqi = ||x_i||^2 via block reduction
  float p = xv * xv;
  #pragma unroll
  for (int off = 32; off > 0; off >>= 1) p += __shfl_down(p, off);
  if (lane == 0) wred[wave] = p;
  __syncthreads();
  const float sqi = wred[0] + wred[1] + wred[2] + wred[3];

  // Distance row, coalesced: wave w owns rows [w*128, w*128+128), 4 rows
  // per iteration (one per 16-lane group). Lane reads 16 floats of its row
  // as 4 float4s at 256B-contiguous segments -> byte-minimal transactions.
  const float4* xiv = (const float4*)xi;
  const int rbase = wave * 128 + rg;
  #pragma unroll 2
  for (int it = 0; it < 32; ++it) {
    const int r = rbase + it * 4;
    const float4* xr = (const float4*)(x + (size_t)r * D);
    float dot = 0.f, sq = 0.f;
    #pragma unroll
    for (int c = 0; c < 4; ++c) {
      float4 b = xr[c * 16 + sub];
      float4 a = xiv[c * 16 + sub];          // 2-way bank alias: free
      dot += a.x * b.x + a.y * b.y + a.z * b.z + a.w * b.w;
      sq  += b.x * b.x + b.y * b.y + b.z * b.z + b.w * b.w;
    }
    // reduce dot/sq over the 16-lane group (large->small: lane sub==0 clean)
    #pragma unroll
    for (int off = 8; off > 0; off >>= 1) {
      dot += __shfl_down(dot, off);
      sq  += __shfl_down(sq, off);
    }
    if (sub == 0) {
      float d = sqrtf(fmaxf(sqi + sq - 2.f * dot, 1e-16f));
      int tj = tgt[r];
      m[r] = (tj != ti) ? d : __builtin_inff(); // +INF masks positives as k
      if (tj == ti && r != i) {
        int s = atomicAdd(&nv, 1);
        clist[s] = d + MARGIN;
      }
    }
  }
  __syncthreads();

  // triplet phase: each thread owns k-pair m[2*tid], m[2*tid+1]
  float sum = 0.f, cnt = 0.f;
  const float2 mk = ((const float2*)m)[tid];
  const int n = nv;
  for (int v = 0; v < n; ++v) {
    float c = clist[v];                       // LDS broadcast
    float a0 = c - mk.x;
    float a1 = c - mk.y;
    sum += fmaxf(a0, 0.f) + fmaxf(a1, 0.f);
    cnt += (a0 > 1e-16f ? 1.f : 0.f) + (a1 > 1e-16f ? 1.f : 0.f);
  }

  // block reduction, one atomic pair per block
  #pragma unroll
  for (int off = 32; off > 0; off >>= 1) {
    sum += __shfl_down(sum, off);
    cnt += __shfl_down(cnt, off);
  }
  __syncthreads();                            // wred reuse
  if (lane == 0) { wred[wave] = sum; wred[4 + wave] = cnt; }
  __syncthreads();
  if (tid == 0) {
    atomicAdd(&acc[0], wred[0] + wred[1] + wred[2] + wred[3]);
    atomicAdd(&acc[1], wred[4] + wred[5] + wred[6] + wred[7]);
  }
}

__global__ void triplet_finalize(const float* __restrict__ acc,
                                 float* __restrict__ out) {
  out[0] = acc[0] / (acc[1] + 1e-16f);
}

extern "C" void kernel_launch(void* const* d_in, const int* in_sizes, int n_in,
                              void* d_out, int out_size, void* d_ws, size_t ws_size,
                              hipStream_t stream) {
  const float* x = (const float*)d_in[0];   // [512, 256] fp32
  const int* tgt = (const int*)d_in[1];     // [512] int32
  float* out = (float*)d_out;               // scalar fp32
  float* acc = (float*)d_ws;                // acc[0]=sum, acc[1]=count

  hipMemsetAsync(acc, 0, 2 * sizeof(float), stream);
  triplet_fused<<<N, 256, 0, stream>>>(x, tgt, acc);
  triplet_finalize<<<1, 1, 0, stream>>>(acc, out);
}

// Round 4
// 86.143 us; speedup vs baseline: 1.3000x; 1.0360x over previous
//
#include <hip/hip_runtime.h>

constexpr int N = 512;   // number of samples
constexpr int D = 256;   // feature dim
#define MARGIN 1.0f

// Block i: compute dist row i with coalesced cooperative row reads
// (wave = 4 rows x 16-lane chunks), compact valid j list (t[j]==t[i], j!=i),
// then sum relu(dist[i][j] - dist[i][k] + margin) over valid (j,k).
// Row visit order is ROTATED per block (bijection over [0,512)) so the 512
// blocks' L2 address streams are decorrelated -> no L2 channel hotspot.
__global__ __launch_bounds__(256) void triplet_fused(
    const float* __restrict__ x, const int* __restrict__ tgt,
    float* __restrict__ acc) {
  __shared__ __align__(16) float xi[D];     // row i staged for broadcast
  __shared__ __align__(16) float m[N];      // dist row, +INF at positives
  __shared__ float clist[N];                // compacted c = d_ap + margin
  __shared__ int nv;
  __shared__ float wred[8];                 // 4 waves x {sum, cnt}

  const int i = blockIdx.x;
  const int tid = threadIdx.x;              // 256 threads = 4 waves
  const int ti = tgt[i];
  const int wave = tid >> 6, lane = tid & 63;
  const int sub = lane & 15, rg = lane >> 4; // chunk-in-row, row-in-group

  // stage xi; keep own element in a register for the sq reduction
  float xv = x[(size_t)i * D + tid];
  xi[tid] = xv;
  if (tid == 0) nv = 0;

  // sqi = ||x_i||^2 via block reduction
  float p = xv * xv;
  #pragma unroll
  for (int off = 32; off > 0; off >>= 1) p += __shfl_down(p, off);
  if (lane == 0) wred[wave] = p;
  __syncthreads();
  const float sqi = wred[0] + wred[1] + wred[2] + wred[3];

  // Distance row, coalesced. Per-block rotation (i*171 is odd-multiplied ->
  // distinct rotation per block) decorrelates the global read streams.
  const float4* xiv = (const float4*)xi;
  const int rot = (i * 171) & (N - 1);
  const int rbase = wave * 128 + rg;
  #pragma unroll 2
  for (int it = 0; it < 32; ++it) {
    const int r = (rbase + it * 4 + rot) & (N - 1);
    const float4* xr = (const float4*)(x + (size_t)r * D);
    float dot = 0.f, sq = 0.f;
    #pragma unroll
    for (int c = 0; c < 4; ++c) {
      float4 b = xr[c * 16 + sub];
      float4 a = xiv[c * 16 + sub];          // 2-way bank alias: free
      dot += a.x * b.x + a.y * b.y + a.z * b.z + a.w * b.w;
      sq  += b.x * b.x + b.y * b.y + b.z * b.z + b.w * b.w;
    }
    // reduce dot/sq over the 16-lane group (lane sub==0 gets clean value)
    #pragma unroll
    for (int off = 8; off > 0; off >>= 1) {
      dot += __shfl_down(dot, off);
      sq  += __shfl_down(sq, off);
    }
    if (sub == 0) {
      float d = sqrtf(fmaxf(sqi + sq - 2.f * dot, 1e-16f));
      int tj = tgt[r];
      m[r] = (tj != ti) ? d : __builtin_inff(); // +INF masks positives as k
      if (tj == ti && r != i) {
        int s = atomicAdd(&nv, 1);
        clist[s] = d + MARGIN;
      }
    }
  }
  __syncthreads();

  // triplet phase: each thread owns k-pair m[2*tid], m[2*tid+1]
  float sum = 0.f, cnt = 0.f;
  const float2 mk = ((const float2*)m)[tid];
  const int n = nv;
  for (int v = 0; v < n; ++v) {
    float c = clist[v];                       // LDS broadcast
    float a0 = c - mk.x;
    float a1 = c - mk.y;
    sum += fmaxf(a0, 0.f) + fmaxf(a1, 0.f);
    cnt += (a0 > 1e-16f ? 1.f : 0.f) + (a1 > 1e-16f ? 1.f : 0.f);
  }

  // block reduction, one atomic pair per block
  #pragma unroll
  for (int off = 32; off > 0; off >>= 1) {
    sum += __shfl_down(sum, off);
    cnt += __shfl_down(cnt, off);
  }
  __syncthreads();                            // wred reuse
  if (lane == 0) { wred[wave] = sum; wred[4 + wave] = cnt; }
  __syncthreads();
  if (tid == 0) {
    atomicAdd(&acc[0], wred[0] + wred[1] + wred[2] + wred[3]);
    atomicAdd(&acc[1], wred[4] + wred[5] + wred[6] + wred[7]);
  }
}

__global__ void triplet_finalize(const float* __restrict__ acc,
                                 float* __restrict__ out) {
  out[0] = acc[0] / (acc[1] + 1e-16f);
}

extern "C" void kernel_launch(void* const* d_in, const int* in_sizes, int n_in,
                              void* d_out, int out_size, void* d_ws, size_t ws_size,
                              hipStream_t stream) {
  const float* x = (const float*)d_in[0];   // [512, 256] fp32
  const int* tgt = (const int*)d_in[1];     // [512] int32
  float* out = (float*)d_out;               // scalar fp32
  float* acc = (float*)d_ws;                // acc[0]=sum, acc[1]=count

  hipMemsetAsync(acc, 0, 2 * sizeof(float), stream);
  triplet_fused<<<N, 256, 0, stream>>>(x, tgt, acc);
  triplet_finalize<<<1, 1, 0, stream>>>(acc, out);
}

// Round 5
// 68.864 us; speedup vs baseline: 1.6262x; 1.2509x over previous
//
#include <hip/hip_runtime.h>

constexpr int N = 512;   // number of samples
constexpr int D = 256;   // feature dim
#define MARGIN 1.0f

// Block i (1024 threads = 16 waves for max occupancy: 512 blocks x 16 waves
// = 32 waves/CU): compute dist row i with coalesced cooperative row reads
// (each 16-lane group owns one row per iteration), compact valid j list
// (t[j]==t[i], j!=i), then sum relu(dist[i][j] - dist[i][k] + margin) over
// valid (j,k). Partials to d_ws; no atomics, no memset dispatch.
__global__ __launch_bounds__(1024, 8) void triplet_fused(
    const float* __restrict__ x, const int* __restrict__ tgt,
    float* __restrict__ part) {
  __shared__ __align__(16) float xi[D];     // row i staged for broadcast
  __shared__ __align__(16) float m[N];      // dist row, +INF at positives
  __shared__ float clist[N];                // compacted c = d_ap + margin
  __shared__ int nv;
  __shared__ float wred[32];                // 16 waves x {sum | cnt}
  __shared__ float sqi_sh;

  const int i = blockIdx.x;
  const int tid = threadIdx.x;              // 1024 threads = 16 waves
  const int ti = tgt[i];
  const int wave = tid >> 6, lane = tid & 63;
  const int sub = lane & 15, rg = lane >> 4; // chunk-in-row, row-in-group

  // stage xi (first 256 threads); everyone contributes to sqi reduction
  float xv = 0.f;
  if (tid < D) { xv = x[(size_t)i * D + tid]; xi[tid] = xv; }
  if (tid == 0) nv = 0;

  // sqi = ||x_i||^2 via block reduction over 16 waves
  float p = xv * xv;
  #pragma unroll
  for (int off = 32; off > 0; off >>= 1) p += __shfl_down(p, off);
  if (lane == 0) wred[wave] = p;
  __syncthreads();
  if (tid == 0) {
    float s = 0.f;
    #pragma unroll
    for (int w = 0; w < 16; ++w) s += wred[w];
    sqi_sh = s;
  }
  __syncthreads();
  const float sqi = sqi_sh;

  // Distance row, coalesced: wave w owns rows {w*32 + it*4 + rg}, it<8.
  // 4 independent 1KB wave-loads in flight per row. Per-block rotation
  // decorrelates the 512 blocks' L2 streams.
  const float4* xiv = (const float4*)xi;
  const int rot = (i * 171) & (N - 1);
  const int rbase = wave * 32 + rg;
  for (int it = 0; it < 8; ++it) {
    const int r = (rbase + it * 4 + rot) & (N - 1);
    const float4* xr = (const float4*)(x + (size_t)r * D);
    float4 b0 = xr[sub];
    float4 b1 = xr[16 + sub];
    float4 b2 = xr[32 + sub];
    float4 b3 = xr[48 + sub];
    float4 a0 = xiv[sub];
    float4 a1 = xiv[16 + sub];
    float4 a2 = xiv[32 + sub];
    float4 a3 = xiv[48 + sub];
    float dot = a0.x*b0.x + a0.y*b0.y + a0.z*b0.z + a0.w*b0.w
              + a1.x*b1.x + a1.y*b1.y + a1.z*b1.z + a1.w*b1.w
              + a2.x*b2.x + a2.y*b2.y + a2.z*b2.z + a2.w*b2.w
              + a3.x*b3.x + a3.y*b3.y + a3.z*b3.z + a3.w*b3.w;
    float sq  = b0.x*b0.x + b0.y*b0.y + b0.z*b0.z + b0.w*b0.w
              + b1.x*b1.x + b1.y*b1.y + b1.z*b1.z + b1.w*b1.w
              + b2.x*b2.x + b2.y*b2.y + b2.z*b2.z + b2.w*b2.w
              + b3.x*b3.x + b3.y*b3.y + b3.z*b3.z + b3.w*b3.w;
    // reduce dot/sq over the 16-lane group (lane sub==0 gets clean value)
    #pragma unroll
    for (int off = 8; off > 0; off >>= 1) {
      dot += __shfl_down(dot, off);
      sq  += __shfl_down(sq, off);
    }
    if (sub == 0) {
      float d = sqrtf(fmaxf(sqi + sq - 2.f * dot, 1e-16f));
      int tj = tgt[r];
      m[r] = (tj != ti) ? d : __builtin_inff(); // +INF masks positives as k
      if (tj == ti && r != i) {
        int s = atomicAdd(&nv, 1);              // LDS atomic, ~7 hits total
        clist[s] = d + MARGIN;
      }
    }
  }
  __syncthreads();

  // triplet phase: thread pair (tid, tid+512) shares element e=tid&511 and
  // splits the clist between them (v = half, half+2, ...)
  float sum = 0.f, cnt = 0.f;
  const int e = tid & 511, half = tid >> 9;
  const float mk = m[e];
  const int n = nv;
  for (int v = half; v < n; v += 2) {
    float a = clist[v] - mk;                  // clist[v] is LDS broadcast
    sum += fmaxf(a, 0.f);
    cnt += (a > 1e-16f ? 1.f : 0.f);
  }

  // block reduction over 16 waves, one partial pair per block
  #pragma unroll
  for (int off = 32; off > 0; off >>= 1) {
    sum += __shfl_down(sum, off);
    cnt += __shfl_down(cnt, off);
  }
  __syncthreads();                            // wred reuse
  if (lane == 0) { wred[wave] = sum; wred[16 + wave] = cnt; }
  __syncthreads();
  if (tid == 0) {
    float s = 0.f, c = 0.f;
    #pragma unroll
    for (int w = 0; w < 16; ++w) { s += wred[w]; c += wred[16 + w]; }
    part[2 * i] = s;
    part[2 * i + 1] = c;
  }
}

// Reduce 512 (sum,cnt) partials and divide.
__global__ __launch_bounds__(512) void triplet_finalize(
    const float* __restrict__ part, float* __restrict__ out) {
  __shared__ float wred[16];
  const int tid = threadIdx.x;
  float s = part[2 * tid], c = part[2 * tid + 1];
  #pragma unroll
  for (int off = 32; off > 0; off >>= 1) {
    s += __shfl_down(s, off);
    c += __shfl_down(c, off);
  }
  int wave = tid >> 6, lane = tid & 63;
  if (lane == 0) { wred[wave] = s; wred[8 + wave] = c; }
  __syncthreads();
  if (tid == 0) {
    float ts = 0.f, tc = 0.f;
    #pragma unroll
    for (int w = 0; w < 8; ++w) { ts += wred[w]; tc += wred[8 + w]; }
    out[0] = ts / (tc + 1e-16f);
  }
}

extern "C" void kernel_launch(void* const* d_in, const int* in_sizes, int n_in,
                              void* d_out, int out_size, void* d_ws, size_t ws_size,
                              hipStream_t stream) {
  const float* x = (const float*)d_in[0];   // [512, 256] fp32
  const int* tgt = (const int*)d_in[1];     // [512] int32
  float* out = (float*)d_out;               // scalar fp32
  float* part = (float*)d_ws;               // 512 x {sum, cnt} partials

  triplet_fused<<<N, 1024, 0, stream>>>(x, tgt, part);
  triplet_finalize<<<1, 512, 0, stream>>>(part, out);
}